// Round 1
// baseline (2876.525 us; speedup 1.0000x reference)
//
#include <hip/hip_runtime.h>
#include <hip/hip_bf16.h>

#define T 256
#define H 400
#define G4 1600   // 4*H
#define WD 300
#define TD 100
#define MLP_H 400
#define NBLK 25   // blocks per direction in lstm kernel

// ---------- math helpers ----------
__device__ __forceinline__ float fexp(float x) {
    return __builtin_amdgcn_exp2f(x * 1.4426950408889634f);
}
__device__ __forceinline__ float sigf(float x) {
    return __builtin_amdgcn_rcpf(1.0f + fexp(-x));
}
__device__ __forceinline__ float tanhf_fast(float x) {
    // 1 - 2/(1+e^{2x}): robust at +/-inf
    return 1.0f - 2.0f * __builtin_amdgcn_rcpf(1.0f + fexp(2.0f * x));
}

// ---------- embedding gather ----------
__global__ void gather_k(const int* __restrict__ words, const int* __restrict__ tags,
                         const float* __restrict__ wemb, const float* __restrict__ temb,
                         float* __restrict__ x0) {
    int t = blockIdx.x;
    int w = words[t], g = tags[t];
    for (int c = threadIdx.x; c < H; c += 128) {
        float v = (c < WD) ? wemb[w * WD + c] : temb[g * TD + (c - WD)];
        x0[t * H + c] = v;
    }
}

// ---------- generic GEMM: out[t][r] = sum_k X[t*ldx+k]*W[r*ldw+wofs+k] + bias1[r]+bias2[r]
// tile 64x64, 256 threads, 4x4 outputs/thread, BK=16
__global__ __launch_bounds__(256) void gemm_tn(
    const float* __restrict__ X, int ldx,
    const float* __restrict__ Wt, int ldw, int wofs,
    const float* __restrict__ bias1, const float* __restrict__ bias2,
    float* __restrict__ out, int ldo, int Rt, int K) {
    __shared__ float Xs[64][17];
    __shared__ float Ws[64][17];
    const int tid = threadIdx.x;
    const int t0 = blockIdx.x * 64, r0 = blockIdx.y * 64;
    const int lr = tid >> 2, kq = (tid & 3) * 4;
    const int ti = tid >> 4, rj = tid & 15;
    float acc[4][4] = {};
    for (int k0 = 0; k0 < K; k0 += 16) {
        float4 xv = *(const float4*)(X + (size_t)(t0 + lr) * ldx + k0 + kq);
        Xs[lr][kq + 0] = xv.x; Xs[lr][kq + 1] = xv.y;
        Xs[lr][kq + 2] = xv.z; Xs[lr][kq + 3] = xv.w;
        int r = r0 + lr;
        float4 wv = make_float4(0.f, 0.f, 0.f, 0.f);
        if (r < Rt) wv = *(const float4*)(Wt + (size_t)r * ldw + wofs + k0 + kq);
        Ws[lr][kq + 0] = wv.x; Ws[lr][kq + 1] = wv.y;
        Ws[lr][kq + 2] = wv.z; Ws[lr][kq + 3] = wv.w;
        __syncthreads();
#pragma unroll
        for (int k = 0; k < 16; k++) {
            float xr[4], wr[4];
#pragma unroll
            for (int m = 0; m < 4; m++) xr[m] = Xs[ti * 4 + m][k];
#pragma unroll
            for (int n = 0; n < 4; n++) wr[n] = Ws[rj * 4 + n][k];
#pragma unroll
            for (int m = 0; m < 4; m++)
#pragma unroll
                for (int n = 0; n < 4; n++)
                    acc[m][n] = fmaf(xr[m], wr[n], acc[m][n]);
        }
        __syncthreads();
    }
    int rq = r0 + rj * 4;
    if (rq < Rt) {
        float b[4];
#pragma unroll
        for (int n = 0; n < 4; n++) {
            int r = rq + n;
            b[n] = (bias1 ? bias1[r] : 0.f) + (bias2 ? bias2[r] : 0.f);
        }
#pragma unroll
        for (int m = 0; m < 4; m++) {
            int t = t0 + ti * 4 + m;
            float4 o;
            o.x = acc[m][0] + b[0]; o.y = acc[m][1] + b[1];
            o.z = acc[m][2] + b[2]; o.w = acc[m][3] + b[3];
            *(float4*)(out + (size_t)t * ldo + rq) = o;
        }
    }
}

// ---------- persistent LSTM layer (both directions) ----------
// grid (NBLK, 2), 256 threads. Each wave: 4 j's, lane = gate(2b) | kg(4b).
__global__ __launch_bounds__(256, 1) void lstm_layer(
    const float* __restrict__ G,     // [2][T][G4], biases folded
    const float* __restrict__ Whh,   // [2][G4][H]
    const float* __restrict__ h0,    // [2][H] for this layer
    const float* __restrict__ c0,    // [2][H]
    float* __restrict__ xout,        // [T][2H], dir d -> cols d*H..
    float* hbuf,                     // [2][2][H]
    int* ctrs) {                     // [2]
    const int tid = threadIdx.x;
    const int wv = tid >> 6, lane = tid & 63;
    const int gate = lane & 3, kg = lane >> 2;
    const int jb = (blockIdx.x * 4 + wv) * 4;
    const int dir = blockIdx.y;
    const float* Wd = Whh + (size_t)dir * G4 * H;
    const float* Gd = G + (size_t)dir * T * G4;
    float* hb = hbuf + dir * 2 * H;
    int* ctr = ctrs + dir;

    // load recurrent weights into registers: 4 j's x 25 k each (this lane's gate)
    float wreg[4][25];
#pragma unroll
    for (int jj = 0; jj < 4; jj++) {
        const float* wrow = Wd + (size_t)(gate * H + jb + jj) * H + kg * 25;
#pragma unroll
        for (int i = 0; i < 25; i++) wreg[jj][i] = wrow[i];
    }
    float c[4];
#pragma unroll
    for (int jj = 0; jj < 4; jj++) c[jj] = c0[dir * H + jb + jj];

    // init h buffer (parity 0)
    if (lane == 0) {
#pragma unroll
        for (int jj = 0; jj < 4; jj++) {
            float hv = h0[dir * H + jb + jj];
            __hip_atomic_store(&hb[jb + jj], hv, __ATOMIC_RELAXED, __HIP_MEMORY_SCOPE_AGENT);
        }
    }
    __syncthreads();
    if (tid == 0) __hip_atomic_fetch_add(ctr, 1, __ATOMIC_RELEASE, __HIP_MEMORY_SCOPE_AGENT);

#pragma clang loop unroll(disable)
    for (int step = 0; step < T; ++step) {
        const int tt = dir ? (T - 1 - step) : step;
        if (tid == 0) {
            const int tgt = NBLK * (step + 1);
            while (__hip_atomic_load(ctr, __ATOMIC_ACQUIRE, __HIP_MEMORY_SCOPE_AGENT) < tgt) {}
        }
        __syncthreads();
        const float* hcur = hb + (step & 1) * H;
        float hreg[25];
#pragma unroll
        for (int i = 0; i < 25; i++)
            hreg[i] = __hip_atomic_load(&hcur[kg * 25 + i], __ATOMIC_RELAXED, __HIP_MEMORY_SCOPE_AGENT);
        float gin[4];
#pragma unroll
        for (int jj = 0; jj < 4; jj++)
            gin[jj] = Gd[(size_t)tt * G4 + gate * H + jb + jj];
        float hnew[4];
#pragma unroll
        for (int jj = 0; jj < 4; jj++) {
            float s = 0.f;
#pragma unroll
            for (int i = 0; i < 25; i++) s = fmaf(wreg[jj][i], hreg[i], s);
            s += __shfl_xor(s, 4);
            s += __shfl_xor(s, 8);
            s += __shfl_xor(s, 16);
            s += __shfl_xor(s, 32);
            float v = s + gin[jj];
            // gate exchange across lanes (gate = lane&3)
            float p = __shfl_xor(v, 1);
            float ev = (gate & 1) ? p : v;
            float od = (gate & 1) ? v : p;
            float ev2 = __shfl_xor(ev, 2);
            float od2 = __shfl_xor(od, 2);
            float iv, fv, gv, ov;
            if (gate & 2) { iv = ev2; fv = od2; gv = ev; ov = od; }
            else          { iv = ev;  fv = od;  gv = ev2; ov = od2; }
            float cn = sigf(fv) * c[jj] + sigf(iv) * tanhf_fast(gv);
            c[jj] = cn;
            hnew[jj] = sigf(ov) * tanhf_fast(cn);
        }
        float* hnext = hb + ((step + 1) & 1) * H;
        if (lane == 0) {
#pragma unroll
            for (int jj = 0; jj < 4; jj++) {
                __hip_atomic_store(&hnext[jb + jj], hnew[jj], __ATOMIC_RELAXED, __HIP_MEMORY_SCOPE_AGENT);
                xout[(size_t)tt * (2 * H) + dir * H + jb + jj] = hnew[jj];
            }
        }
        __syncthreads();
        if (tid == 0) __hip_atomic_fetch_add(ctr, 1, __ATOMIC_RELEASE, __HIP_MEMORY_SCOPE_AGENT);
    }
}

// ---------- fused pairwise scorer ----------
// out[i][j] = sum_k w2[k]*tanh(pi[i][k]+pj[j][k]) + b2 ; diag = 0. (b1 folded into pi)
__global__ __launch_bounds__(256) void scores_k(
    const float* __restrict__ pi, const float* __restrict__ pj,
    const float* __restrict__ w2, const float* __restrict__ b2p,
    float* __restrict__ out) {
    __shared__ float Ps[16][401];
    __shared__ float Qs[16][401];
    __shared__ float w2s[400];
    const int tid = threadIdx.x;
    const int i0 = blockIdx.y * 16, j0 = blockIdx.x * 16;
    for (int r = 0; r < 16; r++) {
        for (int k = tid; k < MLP_H; k += 256) {
            Ps[r][k] = pi[(size_t)(i0 + r) * MLP_H + k];
            Qs[r][k] = pj[(size_t)(j0 + r) * MLP_H + k];
        }
    }
    for (int k = tid; k < MLP_H; k += 256) w2s[k] = w2[k];
    __syncthreads();
    const int ti = tid >> 4, tj = tid & 15;
    float acc = 0.f;
#pragma unroll 4
    for (int k = 0; k < MLP_H; k++) {
        float x = Ps[ti][k] + Qs[tj][k];
        acc = fmaf(w2s[k], tanhf_fast(x), acc);
    }
    const int i = i0 + ti, j = j0 + tj;
    out[(size_t)i * T + j] = (i == j) ? 0.f : (acc + b2p[0]);
}

extern "C" void kernel_launch(void* const* d_in, const int* in_sizes, int n_in,
                              void* d_out, int out_size, void* d_ws, size_t ws_size,
                              hipStream_t stream) {
    const int*   words = (const int*)d_in[0];
    const int*   tags  = (const int*)d_in[1];
    const float* wemb  = (const float*)d_in[2];
    const float* temb  = (const float*)d_in[3];
    const float* Wih0  = (const float*)d_in[4];
    const float* Whh0  = (const float*)d_in[5];
    const float* bih0  = (const float*)d_in[6];
    const float* bhh0  = (const float*)d_in[7];
    const float* Wih1  = (const float*)d_in[8];
    const float* Whh1  = (const float*)d_in[9];
    const float* bih1  = (const float*)d_in[10];
    const float* bhh1  = (const float*)d_in[11];
    const float* W1    = (const float*)d_in[12];
    const float* b1    = (const float*)d_in[13];
    const float* W2    = (const float*)d_in[14];
    const float* b2    = (const float*)d_in[15];
    const float* h0    = (const float*)d_in[16];
    const float* c0    = (const float*)d_in[17];
    float* out = (float*)d_out;

    float* W = (float*)d_ws;
    float* x0   = W;                 // 256*400
    float* x1   = W + 102400;        // 256*800
    float* hvec = W + 307200;        // 256*800
    float* Gb   = W + 512000;        // 2*256*1600 (reused for both layers)
    float* pi   = W + 1331200;       // 256*400
    float* pj   = W + 1433600;       // 256*400
    float* hbuf = W + 1536000;       // 2*2*400
    int*   ctrs = (int*)(W + 1538048); // 4 ints

    hipMemsetAsync(ctrs, 0, 4 * sizeof(int), stream);

    // 1. embedding gather
    gather_k<<<T, 128, 0, stream>>>(words, tags, wemb, temb, x0);

    // 2. layer-0 gate inputs: G[d][t][r]
    for (int d = 0; d < 2; d++) {
        gemm_tn<<<dim3(4, 25), 256, 0, stream>>>(
            x0, H, Wih0 + (size_t)d * G4 * H, H, 0,
            bih0 + d * G4, bhh0 + d * G4,
            Gb + (size_t)d * T * G4, G4, G4, H);
    }
    // 3. LSTM layer 0
    lstm_layer<<<dim3(NBLK, 2), 256, 0, stream>>>(
        Gb, Whh0, h0, c0, x1, hbuf, ctrs);

    // 4. layer-1 gate inputs (K=800)
    for (int d = 0; d < 2; d++) {
        gemm_tn<<<dim3(4, 25), 256, 0, stream>>>(
            x1, 2 * H, Wih1 + (size_t)d * G4 * (2 * H), 2 * H, 0,
            bih1 + d * G4, bhh1 + d * G4,
            Gb + (size_t)d * T * G4, G4, G4, 2 * H);
    }
    // 5. LSTM layer 1
    lstm_layer<<<dim3(NBLK, 2), 256, 0, stream>>>(
        Gb, Whh1, h0 + 2 * H, c0 + 2 * H, hvec, hbuf, ctrs + 2);

    // 6. pi = hvec @ W1a.T + b1 ; pj = hvec @ W1b.T
    gemm_tn<<<dim3(4, 7), 256, 0, stream>>>(
        hvec, 2 * H, W1, G4, 0, b1, nullptr, pi, MLP_H, MLP_H, 2 * H);
    gemm_tn<<<dim3(4, 7), 256, 0, stream>>>(
        hvec, 2 * H, W1, G4, 2 * H, nullptr, nullptr, pj, MLP_H, MLP_H, 2 * H);

    // 7. fused pairwise scores
    scores_k<<<dim3(16, 16), 256, 0, stream>>>(pi, pj, W2, b2, out);
}